// Round 3
// baseline (245.330 us; speedup 1.0000x reference)
//
#include <hip/hip_runtime.h>

// EMA (adjust=True, alpha=2/26) over x[32][4096][256] f32.
// Recurrence: e_t = (alpha*x_t + oma*e_{t-1}) / w_t, w_t = max(1-oma^(t+1), 1e-10).
//
// Design: data-independent coefficients => chunk the T axis into 8 chunks of 512
// per batch (256 blocks total) and give each chunk>0 a 256-row warm-up halo
// starting from e=0. Init influence decays by oma^256 ~ 1.2e-9 (below fp32
// rounding of O(1) outputs) -> no cross-block communication needed.
// For t >= 256, w_t rounds to exactly 1.0f, so all halo/body steps of chunks>=1
// are a bare fma. Chunk 0 computes the exact prefix with per-t w.

namespace {

constexpr int kT = 4096;
constexpr int kF4 = 64;        // 256 floats / float4
constexpr int kL = 512;        // chunk length (rows)
constexpr int kHalo = 256;     // warm-up rows for chunks > 0
constexpr int kNC = kT / kL;   // 8 chunks per batch
constexpr int kG = 16;         // rows per pipelined group

constexpr double kAlphaD = 2.0 / 26.0;
constexpr float kAlpha = (float)kAlphaD;          // matches jnp.asarray(ALPHA, f32)
constexpr float kOma   = (float)(1.0 - kAlphaD);  // matches jnp.asarray(1-ALPHA, f32)

__device__ __forceinline__ void load_group(const float4* __restrict__ p,
                                           float4 (&buf)[kG]) {
#pragma unroll
  for (int i = 0; i < kG; ++i) buf[i] = p[i * kF4];
}

__device__ __forceinline__ void store_group(float4* __restrict__ p,
                                            const float4 (&buf)[kG]) {
#pragma unroll
  for (int i = 0; i < kG; ++i) p[i * kF4] = buf[i];
}

__device__ __forceinline__ void step_fast(float4& e, const float4 v) {
  e.x = fmaf(kOma, e.x, kAlpha * v.x);
  e.y = fmaf(kOma, e.y, kAlpha * v.y);
  e.z = fmaf(kOma, e.z, kAlpha * v.z);
  e.w = fmaf(kOma, e.w, kAlpha * v.w);
}

// Fast path (w==1.0f exactly): e = fma(oma, e, alpha*x); result left in buf.
__device__ __forceinline__ void group_fast(float4 (&buf)[kG], float4& e) {
#pragma unroll
  for (int i = 0; i < kG; ++i) {
    step_fast(e, buf[i]);
    buf[i] = e;
  }
}

}  // namespace

__global__ __launch_bounds__(64, 1) void ema_kernel(const float* __restrict__ x,
                                                    float* __restrict__ out) {
  const int blk = blockIdx.x;
  const int c = blk & (kNC - 1);   // chunk index within batch
  const int b = blk / kNC;         // batch index
  const int lane = threadIdx.x;    // 0..63, owns 4 consecutive f's

  const float4* xb = reinterpret_cast<const float4*>(x) + (size_t)b * kT * kF4 + lane;
  float4* ob = reinterpret_cast<float4*>(out) + (size_t)b * kT * kF4 + lane;

  float4 e = make_float4(0.f, 0.f, 0.f, 0.f);
  float4 bufA[kG], bufB[kG];

  if (c == 0) {
    // Exact prefix: t = 0..511 with per-t w.
    const float4* px = xb;
    float4* po = ob;
    double p = (double)kOma;  // will hold oma^(t+1) after the per-t multiply
    constexpr int NGrp = kL / kG;  // 32 (even)

    load_group(px, bufA);
    px += kG * kF4;
    for (int g = 0; g < NGrp; g += 2) {
      load_group(px, bufB);
      px += kG * kF4;
      {
        const int tbase = g * kG;
#pragma unroll
        for (int i = 0; i < kG; ++i) {
          const float4 v = bufA[i];
          if (tbase + i == 0) {
            e = v;  // e0 = x[:,0,:]
          } else {
            p *= (double)kOma;  // p = oma^(t+1)
            const float w = fmaxf(1.0f - (float)p, 1e-10f);
            const float inv = 1.0f / w;
            step_fast(e, v);
            e.x *= inv; e.y *= inv; e.z *= inv; e.w *= inv;
          }
          bufA[i] = e;
        }
      }
      store_group(po, bufA);
      po += kG * kF4;
      if (g + 2 < NGrp) {
        load_group(px, bufA);
        px += kG * kF4;
      }
      {
#pragma unroll
        for (int i = 0; i < kG; ++i) {
          const float4 v = bufB[i];
          p *= (double)kOma;
          const float w = fmaxf(1.0f - (float)p, 1e-10f);
          const float inv = 1.0f / w;
          step_fast(e, v);
          e.x *= inv; e.y *= inv; e.z *= inv; e.w *= inv;
          bufB[i] = e;
        }
      }
      store_group(po, bufB);
      po += kG * kF4;
    }
  } else {
    // Chunks 1..7: 256-row warm-up halo (no store) + 512-row body (store).
    // All rows have t >= 256, so w_t == 1.0f exactly -> bare fma.
    const float4* px = xb + (size_t)(c * kL - kHalo) * kF4;
    float4* po = ob + (size_t)(c * kL) * kF4;
    constexpr int NGrp = (kHalo + kL) / kG;  // 48 (even)
    constexpr int HGrp = kHalo / kG;         // 16 halo groups

    load_group(px, bufA);
    px += kG * kF4;
    for (int g = 0; g < NGrp; g += 2) {
      load_group(px, bufB);
      px += kG * kF4;
      group_fast(bufA, e);
      if (g >= HGrp) {
        store_group(po, bufA);
        po += kG * kF4;
      }
      if (g + 2 < NGrp) {
        load_group(px, bufA);
        px += kG * kF4;
      }
      group_fast(bufB, e);
      if (g + 1 >= HGrp) {
        store_group(po, bufB);
        po += kG * kF4;
      }
    }
  }
}

extern "C" void kernel_launch(void* const* d_in, const int* in_sizes, int n_in,
                              void* d_out, int out_size, void* d_ws, size_t ws_size,
                              hipStream_t stream) {
  (void)in_sizes; (void)n_in; (void)d_ws; (void)ws_size; (void)out_size;
  const float* x = reinterpret_cast<const float*>(d_in[0]);
  float* out = reinterpret_cast<float*>(d_out);
  constexpr int kBatches = 32;
  dim3 grid(kBatches * kNC);  // 256 blocks
  dim3 block(64);
  hipLaunchKernelGGL(ema_kernel, grid, block, 0, stream, x, out);
}